// Round 1
// baseline (1409.761 us; speedup 1.0000x reference)
//
#include <hip/hip_runtime.h>

#define DIM 64

// ---------------------------------------------------------------------------
// Kernel 1: edge scatter. 16 lanes per edge; each lane handles 4 dims via
// float4 gather from x[col] and 4 global atomicAdds into agg[row].
// ---------------------------------------------------------------------------
__global__ __launch_bounds__(256) void scatter_kernel(
    const float* __restrict__ x, const int* __restrict__ erow,
    const int* __restrict__ ecol, const float* __restrict__ eval,
    float* __restrict__ agg, int E) {
  int t = blockIdx.x * 256 + threadIdx.x;
  int e = t >> 4;
  if (e >= E) return;
  int lid = t & 15;
  int r = erow[e];
  int c = ecol[e];
  float v = eval[e];
  const float4 xv =
      *reinterpret_cast<const float4*>(x + (size_t)c * DIM + lid * 4);
  float* dst = agg + (size_t)r * DIM + lid * 4;
  atomicAdd(dst + 0, v * xv.x);
  atomicAdd(dst + 1, v * xv.y);
  atomicAdd(dst + 2, v * xv.z);
  atomicAdd(dst + 3, v * xv.w);
}

// ---------------------------------------------------------------------------
// Kernel 2: fused Linear (h = agg @ W^T + b) + LayerNorm + ReLU.
// One wave processes 4 nodes; lane index = output dim d.
// W^T staged in LDS padded to stride 65 (bank = (k+d)%32 -> 2-way, free).
// agg row lives distributed across lanes; broadcast via v_readlane (k is a
// compile-time constant after full unroll -> SGPR operand into v_fmac).
// ---------------------------------------------------------------------------
__device__ __forceinline__ float readlane_f(float v, int l) {
  return __uint_as_float(__builtin_amdgcn_readlane(__float_as_uint(v), l));
}

__global__ __launch_bounds__(256) void fused_linear_ln_relu(
    const float* __restrict__ agg, const float* __restrict__ W,
    const float* __restrict__ bias, const float* __restrict__ gamma,
    const float* __restrict__ beta, float* __restrict__ out, int N) {
  __shared__ float Wt[64 * 65];
  // Stage W^T: read W coalesced, write transposed (padded stride -> no conflict)
  for (int i = threadIdx.x; i < 64 * 64; i += 256) {
    int d = i >> 6, k = i & 63;
    Wt[k * 65 + d] = W[i];
  }
  __syncthreads();

  const int wave = threadIdx.x >> 6;
  const int lane = threadIdx.x & 63;
  const int node0 = blockIdx.x * 16 + wave * 4;

  // Load 4 agg rows, one element per lane (lane = k index here).
  float a0 = 0.f, a1 = 0.f, a2 = 0.f, a3 = 0.f;
  if (node0 + 0 < N) a0 = agg[(size_t)(node0 + 0) * DIM + lane];
  if (node0 + 1 < N) a1 = agg[(size_t)(node0 + 1) * DIM + lane];
  if (node0 + 2 < N) a2 = agg[(size_t)(node0 + 2) * DIM + lane];
  if (node0 + 3 < N) a3 = agg[(size_t)(node0 + 3) * DIM + lane];

  float acc0 = 0.f, acc1 = 0.f, acc2 = 0.f, acc3 = 0.f;
#pragma unroll
  for (int k = 0; k < 64; ++k) {
    float w = Wt[k * 65 + lane];  // lane = d
    acc0 = fmaf(readlane_f(a0, k), w, acc0);
    acc1 = fmaf(readlane_f(a1, k), w, acc1);
    acc2 = fmaf(readlane_f(a2, k), w, acc2);
    acc3 = fmaf(readlane_f(a3, k), w, acc3);
  }

  const float bv = bias[lane];
  const float gv = gamma[lane];
  const float btv = beta[lane];

  float accs[4] = {acc0, acc1, acc2, acc3};
#pragma unroll
  for (int j = 0; j < 4; ++j) {
    int node = node0 + j;
    if (node >= N) continue;
    float h = accs[j] + bv;
    float s1 = h, s2 = h * h;
#pragma unroll
    for (int off = 32; off; off >>= 1) {
      s1 += __shfl_xor(s1, off, 64);
      s2 += __shfl_xor(s2, off, 64);
    }
    float mu = s1 * (1.0f / 64.0f);
    float var = s2 * (1.0f / 64.0f) - mu * mu;
    float inv = rsqrtf(var + 1e-5f);
    float y = (h - mu) * inv * gv + btv;
    out[(size_t)node * DIM + lane] = fmaxf(y, 0.0f);
  }
}

// ---------------------------------------------------------------------------
extern "C" void kernel_launch(void* const* d_in, const int* in_sizes, int n_in,
                              void* d_out, int out_size, void* d_ws,
                              size_t ws_size, hipStream_t stream) {
  const float* x = (const float*)d_in[0];
  const int* erow = (const int*)d_in[1];
  const int* ecol = (const int*)d_in[2];
  const float* eval = (const float*)d_in[3];
  const float* W = (const float*)d_in[4];
  const float* bias = (const float*)d_in[5];
  const float* gamma = (const float*)d_in[6];
  const float* beta = (const float*)d_in[7];
  float* out = (float*)d_out;

  const int N = in_sizes[0] / DIM;
  const int E = in_sizes[1];
  const size_t agg_bytes = (size_t)N * DIM * sizeof(float);

  // agg buffer: prefer workspace; fall back to in-place on d_out (safe: the
  // fused kernel fully reads each node's agg row into registers before
  // writing that row).
  float* agg = (ws_size >= agg_bytes) ? (float*)d_ws : out;

  hipMemsetAsync(agg, 0, agg_bytes, stream);

  {
    long long total = (long long)E * 16;
    int blocks = (int)((total + 255) / 256);
    scatter_kernel<<<blocks, 256, 0, stream>>>(x, erow, ecol, eval, agg, E);
  }
  {
    int blocks = (N + 15) / 16;
    fused_linear_ln_relu<<<blocks, 256, 0, stream>>>(agg, W, bias, gamma, beta,
                                                     out, N);
  }
}

// Round 2
// 304.492 us; speedup vs baseline: 4.6299x; 4.6299x over previous
//
#include <hip/hip_runtime.h>

#define DIM 64

// ===========================================================================
// Fallback path (used only if ws_size is too small for CSR build):
// atomic scatter + fused linear/LN/ReLU  (round-0 working version)
// ===========================================================================
__global__ __launch_bounds__(256) void scatter_kernel(
    const float* __restrict__ x, const int* __restrict__ erow,
    const int* __restrict__ ecol, const float* __restrict__ eval,
    float* __restrict__ agg, int E) {
  int t = blockIdx.x * 256 + threadIdx.x;
  int e = t >> 4;
  if (e >= E) return;
  int lid = t & 15;
  int r = erow[e];
  int c = ecol[e];
  float v = eval[e];
  const float4 xv =
      *reinterpret_cast<const float4*>(x + (size_t)c * DIM + lid * 4);
  float* dst = agg + (size_t)r * DIM + lid * 4;
  atomicAdd(dst + 0, v * xv.x);
  atomicAdd(dst + 1, v * xv.y);
  atomicAdd(dst + 2, v * xv.z);
  atomicAdd(dst + 3, v * xv.w);
}

__device__ __forceinline__ float readlane_f(float v, int l) {
  return __uint_as_float(__builtin_amdgcn_readlane(__float_as_uint(v), l));
}

__global__ __launch_bounds__(256) void fused_linear_ln_relu(
    const float* __restrict__ agg, const float* __restrict__ W,
    const float* __restrict__ bias, const float* __restrict__ gamma,
    const float* __restrict__ beta, float* __restrict__ out, int N) {
  __shared__ float Wt[64 * 65];
  for (int i = threadIdx.x; i < 64 * 64; i += 256) {
    int d = i >> 6, k = i & 63;
    Wt[k * 65 + d] = W[i];
  }
  __syncthreads();

  const int wave = threadIdx.x >> 6;
  const int lane = threadIdx.x & 63;
  const int node0 = blockIdx.x * 16 + wave * 4;

  float a0 = 0.f, a1 = 0.f, a2 = 0.f, a3 = 0.f;
  if (node0 + 0 < N) a0 = agg[(size_t)(node0 + 0) * DIM + lane];
  if (node0 + 1 < N) a1 = agg[(size_t)(node0 + 1) * DIM + lane];
  if (node0 + 2 < N) a2 = agg[(size_t)(node0 + 2) * DIM + lane];
  if (node0 + 3 < N) a3 = agg[(size_t)(node0 + 3) * DIM + lane];

  float acc0 = 0.f, acc1 = 0.f, acc2 = 0.f, acc3 = 0.f;
#pragma unroll
  for (int k = 0; k < 64; ++k) {
    float w = Wt[k * 65 + lane];
    acc0 = fmaf(readlane_f(a0, k), w, acc0);
    acc1 = fmaf(readlane_f(a1, k), w, acc1);
    acc2 = fmaf(readlane_f(a2, k), w, acc2);
    acc3 = fmaf(readlane_f(a3, k), w, acc3);
  }

  const float bv = bias[lane];
  const float gv = gamma[lane];
  const float btv = beta[lane];

  float accs[4] = {acc0, acc1, acc2, acc3};
#pragma unroll
  for (int j = 0; j < 4; ++j) {
    int node = node0 + j;
    if (node >= N) continue;
    float h = accs[j] + bv;
    float s1 = h, s2 = h * h;
#pragma unroll
    for (int off = 32; off; off >>= 1) {
      s1 += __shfl_xor(s1, off, 64);
      s2 += __shfl_xor(s2, off, 64);
    }
    float mu = s1 * (1.0f / 64.0f);
    float var = s2 * (1.0f / 64.0f) - mu * mu;
    float inv = rsqrtf(var + 1e-5f);
    float y = (h - mu) * inv * gv + btv;
    out[(size_t)node * DIM + lane] = fmaxf(y, 0.0f);
  }
}

// ===========================================================================
// CSR-build path
// ===========================================================================

// 1) histogram of edge_row into cnt[] (int atomics, L2-resident)
__global__ __launch_bounds__(256) void hist_kernel(const int* __restrict__ erow,
                                                   int* __restrict__ cnt,
                                                   int E) {
  int e = blockIdx.x * 256 + threadIdx.x;
  if (e < E) atomicAdd(&cnt[erow[e]], 1);
}

// 2a) per-block exclusive scan (1024 elems/block, in place) + block totals
__global__ __launch_bounds__(256) void scan1_kernel(int* __restrict__ data,
                                                    int* __restrict__ partials,
                                                    int N) {
  __shared__ int wsum[4];
  int t = threadIdx.x;
  int base = blockIdx.x * 1024 + t * 4;
  int v0 = (base + 0 < N) ? data[base + 0] : 0;
  int v1 = (base + 1 < N) ? data[base + 1] : 0;
  int v2 = (base + 2 < N) ? data[base + 2] : 0;
  int v3 = (base + 3 < N) ? data[base + 3] : 0;
  int s = v0 + v1 + v2 + v3;
  int ps = s;
  int lane = t & 63;
#pragma unroll
  for (int off = 1; off < 64; off <<= 1) {
    int n = __shfl_up(ps, off, 64);
    if (lane >= off) ps += n;
  }
  if (lane == 63) wsum[t >> 6] = ps;
  __syncthreads();
  int woff = 0;
  for (int w = 0; w < (t >> 6); ++w) woff += wsum[w];
  int ex = woff + ps - s;
  if (base + 0 < N) data[base + 0] = ex;
  if (base + 1 < N) data[base + 1] = ex + v0;
  if (base + 2 < N) data[base + 2] = ex + v0 + v1;
  if (base + 3 < N) data[base + 3] = ex + v0 + v1 + v2;
  if (t == 255) partials[blockIdx.x] = woff + ps;
}

// 2b) exclusive scan of block totals (single block; supports nb <= 256)
__global__ __launch_bounds__(256) void scan2_kernel(int* __restrict__ partials,
                                                    int nb) {
  __shared__ int wsum[4];
  int t = threadIdx.x;
  int v = (t < nb) ? partials[t] : 0;
  int ps = v;
  int lane = t & 63;
#pragma unroll
  for (int off = 1; off < 64; off <<= 1) {
    int n = __shfl_up(ps, off, 64);
    if (lane >= off) ps += n;
  }
  if (lane == 63) wsum[t >> 6] = ps;
  __syncthreads();
  int woff = 0;
  for (int w = 0; w < (t >> 6); ++w) woff += wsum[w];
  if (t < nb) partials[t] = woff + ps - v;
}

// 2c) add block offsets -> final row_start; copy to fill[]; set row_start[N]=E
__global__ __launch_bounds__(256) void scan3_kernel(int* __restrict__ row_start,
                                                    int* __restrict__ fill,
                                                    const int* __restrict__ partials,
                                                    int N, int E) {
  int i = blockIdx.x * 256 + threadIdx.x;
  if (i < N) {
    int v = row_start[i] + partials[i >> 10];
    row_start[i] = v;
    fill[i] = v;
  }
  if (i == N) row_start[N] = E;
}

// 3) scatter edges into CSR slots
__global__ __launch_bounds__(256) void scatter_sort_kernel(
    const int* __restrict__ erow, const int* __restrict__ ecol,
    const float* __restrict__ eval, int* __restrict__ fill,
    int* __restrict__ scol, float* __restrict__ sval, int E) {
  int e = blockIdx.x * 256 + threadIdx.x;
  if (e >= E) return;
  int r = erow[e];
  int pos = atomicAdd(&fill[r], 1);
  scol[pos] = ecol[e];
  sval[pos] = eval[e];
}

// 4) fused gather (SpMM) + Linear + LayerNorm + ReLU.
//    Block = 256 = 4 waves; each wave owns 4 nodes via 16-lane groups.
__global__ __launch_bounds__(256) void fused_gather_linear_ln(
    const float* __restrict__ x, const int* __restrict__ scol,
    const float* __restrict__ sval, const int* __restrict__ row_start,
    const float* __restrict__ W, const float* __restrict__ bias,
    const float* __restrict__ gamma, const float* __restrict__ beta,
    float* __restrict__ out, int N) {
  __shared__ float Wt[64 * 65];
  __shared__ float xch[4][256];
  for (int i = threadIdx.x; i < 64 * 64; i += 256) {
    int d = i >> 6, k = i & 63;
    Wt[k * 65 + d] = W[i];
  }

  const int wave = threadIdx.x >> 6;
  const int lane = threadIdx.x & 63;
  const int grp = lane >> 4;   // which of the wave's 4 nodes
  const int lid = lane & 15;   // 16 lanes x float4 = 64 dims
  const int node0 = blockIdx.x * 16 + wave * 4;
  const int node = node0 + grp;

  float4 acc = make_float4(0.f, 0.f, 0.f, 0.f);
  if (node < N) {
    int s = row_start[node];
    int en = row_start[node + 1];
    int j = s;
    for (; j + 1 < en; j += 2) {
      int c0 = scol[j], c1 = scol[j + 1];
      float v0 = sval[j], v1 = sval[j + 1];
      const float4 x0 =
          *reinterpret_cast<const float4*>(x + (size_t)c0 * DIM + lid * 4);
      const float4 x1 =
          *reinterpret_cast<const float4*>(x + (size_t)c1 * DIM + lid * 4);
      acc.x = fmaf(v0, x0.x, acc.x);
      acc.y = fmaf(v0, x0.y, acc.y);
      acc.z = fmaf(v0, x0.z, acc.z);
      acc.w = fmaf(v0, x0.w, acc.w);
      acc.x = fmaf(v1, x1.x, acc.x);
      acc.y = fmaf(v1, x1.y, acc.y);
      acc.z = fmaf(v1, x1.z, acc.z);
      acc.w = fmaf(v1, x1.w, acc.w);
    }
    if (j < en) {
      int c0 = scol[j];
      float v0 = sval[j];
      const float4 x0 =
          *reinterpret_cast<const float4*>(x + (size_t)c0 * DIM + lid * 4);
      acc.x = fmaf(v0, x0.x, acc.x);
      acc.y = fmaf(v0, x0.y, acc.y);
      acc.z = fmaf(v0, x0.z, acc.z);
      acc.w = fmaf(v0, x0.w, acc.w);
    }
  }
  __syncthreads();  // covers Wt staging too
  *reinterpret_cast<float4*>(&xch[wave][grp * 64 + lid * 4]) = acc;
  __syncthreads();

  // lane-exchange: a_j = agg[node0+j][lane]  (lane = k index)
  float a0 = xch[wave][0 * 64 + lane];
  float a1 = xch[wave][1 * 64 + lane];
  float a2 = xch[wave][2 * 64 + lane];
  float a3 = xch[wave][3 * 64 + lane];

  float acc0 = 0.f, acc1 = 0.f, acc2 = 0.f, acc3 = 0.f;
#pragma unroll
  for (int k = 0; k < 64; ++k) {
    float w = Wt[k * 65 + lane];  // lane = d
    acc0 = fmaf(readlane_f(a0, k), w, acc0);
    acc1 = fmaf(readlane_f(a1, k), w, acc1);
    acc2 = fmaf(readlane_f(a2, k), w, acc2);
    acc3 = fmaf(readlane_f(a3, k), w, acc3);
  }

  const float bv = bias[lane];
  const float gv = gamma[lane];
  const float btv = beta[lane];

  float accs[4] = {acc0, acc1, acc2, acc3};
#pragma unroll
  for (int jj = 0; jj < 4; ++jj) {
    int nd = node0 + jj;
    if (nd >= N) continue;
    float h = accs[jj] + bv;
    float s1 = h, s2 = h * h;
#pragma unroll
    for (int off = 32; off; off >>= 1) {
      s1 += __shfl_xor(s1, off, 64);
      s2 += __shfl_xor(s2, off, 64);
    }
    float mu = s1 * (1.0f / 64.0f);
    float var = s2 * (1.0f / 64.0f) - mu * mu;
    float inv = rsqrtf(var + 1e-5f);
    float y = (h - mu) * inv * gv + btv;
    out[(size_t)nd * DIM + lane] = fmaxf(y, 0.0f);
  }
}

// ===========================================================================
extern "C" void kernel_launch(void* const* d_in, const int* in_sizes, int n_in,
                              void* d_out, int out_size, void* d_ws,
                              size_t ws_size, hipStream_t stream) {
  const float* x = (const float*)d_in[0];
  const int* erow = (const int*)d_in[1];
  const int* ecol = (const int*)d_in[2];
  const float* eval = (const float*)d_in[3];
  const float* W = (const float*)d_in[4];
  const float* bias = (const float*)d_in[5];
  const float* gamma = (const float*)d_in[6];
  const float* beta = (const float*)d_in[7];
  float* out = (float*)d_out;

  const int N = in_sizes[0] / DIM;
  const int E = in_sizes[1];

  // workspace layout for CSR path
  const int nblk_scan = (N + 1023) / 1024;
  size_t need = (size_t)((N + 1) + N + 256 + E) * sizeof(int) +
                (size_t)E * sizeof(float) + 64;

  if (ws_size >= need && nblk_scan <= 256) {
    int* row_start = (int*)d_ws;           // N+1
    int* fill = row_start + (N + 1);       // N
    int* partials = fill + N;              // 256
    int* scol = partials + 256;            // E
    float* sval = (float*)(scol + E);      // E

    hipMemsetAsync(row_start, 0, (size_t)(N + 1) * sizeof(int), stream);

    int eblk = (E + 255) / 256;
    hist_kernel<<<eblk, 256, 0, stream>>>(erow, row_start, E);
    scan1_kernel<<<nblk_scan, 256, 0, stream>>>(row_start, partials, N);
    scan2_kernel<<<1, 256, 0, stream>>>(partials, nblk_scan);
    scan3_kernel<<<(N + 256) / 256, 256, 0, stream>>>(row_start, fill,
                                                      partials, N, E);
    scatter_sort_kernel<<<eblk, 256, 0, stream>>>(erow, ecol, eval, fill, scol,
                                                  sval, E);
    fused_gather_linear_ln<<<(N + 15) / 16, 256, 0, stream>>>(
        x, scol, sval, row_start, W, bias, gamma, beta, out, N);
  } else {
    // fallback: atomic scatter path
    const size_t agg_bytes = (size_t)N * DIM * sizeof(float);
    float* agg = (ws_size >= agg_bytes) ? (float*)d_ws : out;
    hipMemsetAsync(agg, 0, agg_bytes, stream);
    long long total = (long long)E * 16;
    int blocks = (int)((total + 255) / 256);
    scatter_kernel<<<blocks, 256, 0, stream>>>(x, erow, ecol, eval, agg, E);
    fused_linear_ln_relu<<<(N + 15) / 16, 256, 0, stream>>>(agg, W, bias,
                                                            gamma, beta, out, N);
  }
}

// Round 3
// 293.825 us; speedup vs baseline: 4.7980x; 1.0363x over previous
//
#include <hip/hip_runtime.h>

#define DIM 64

// ===========================================================================
// Fallback path (used only if ws_size is too small for CSR build)
// ===========================================================================
__global__ __launch_bounds__(256) void scatter_kernel(
    const float* __restrict__ x, const int* __restrict__ erow,
    const int* __restrict__ ecol, const float* __restrict__ eval,
    float* __restrict__ agg, int E) {
  int t = blockIdx.x * 256 + threadIdx.x;
  int e = t >> 4;
  if (e >= E) return;
  int lid = t & 15;
  int r = erow[e];
  int c = ecol[e];
  float v = eval[e];
  const float4 xv =
      *reinterpret_cast<const float4*>(x + (size_t)c * DIM + lid * 4);
  float* dst = agg + (size_t)r * DIM + lid * 4;
  atomicAdd(dst + 0, v * xv.x);
  atomicAdd(dst + 1, v * xv.y);
  atomicAdd(dst + 2, v * xv.z);
  atomicAdd(dst + 3, v * xv.w);
}

__device__ __forceinline__ float readlane_f(float v, int l) {
  return __uint_as_float(__builtin_amdgcn_readlane(__float_as_uint(v), l));
}

__global__ __launch_bounds__(256) void fused_linear_ln_relu(
    const float* __restrict__ agg, const float* __restrict__ W,
    const float* __restrict__ bias, const float* __restrict__ gamma,
    const float* __restrict__ beta, float* __restrict__ out, int N) {
  __shared__ float Wt[64 * 65];
  for (int i = threadIdx.x; i < 64 * 64; i += 256) {
    int d = i >> 6, k = i & 63;
    Wt[k * 65 + d] = W[i];
  }
  __syncthreads();

  const int wave = threadIdx.x >> 6;
  const int lane = threadIdx.x & 63;
  const int node0 = blockIdx.x * 16 + wave * 4;

  float a0 = 0.f, a1 = 0.f, a2 = 0.f, a3 = 0.f;
  if (node0 + 0 < N) a0 = agg[(size_t)(node0 + 0) * DIM + lane];
  if (node0 + 1 < N) a1 = agg[(size_t)(node0 + 1) * DIM + lane];
  if (node0 + 2 < N) a2 = agg[(size_t)(node0 + 2) * DIM + lane];
  if (node0 + 3 < N) a3 = agg[(size_t)(node0 + 3) * DIM + lane];

  float acc0 = 0.f, acc1 = 0.f, acc2 = 0.f, acc3 = 0.f;
#pragma unroll
  for (int k = 0; k < 64; ++k) {
    float w = Wt[k * 65 + lane];
    acc0 = fmaf(readlane_f(a0, k), w, acc0);
    acc1 = fmaf(readlane_f(a1, k), w, acc1);
    acc2 = fmaf(readlane_f(a2, k), w, acc2);
    acc3 = fmaf(readlane_f(a3, k), w, acc3);
  }

  const float bv = bias[lane];
  const float gv = gamma[lane];
  const float btv = beta[lane];

  float accs[4] = {acc0, acc1, acc2, acc3};
#pragma unroll
  for (int j = 0; j < 4; ++j) {
    int node = node0 + j;
    if (node >= N) continue;
    float h = accs[j] + bv;
    float s1 = h, s2 = h * h;
#pragma unroll
    for (int off = 32; off; off >>= 1) {
      s1 += __shfl_xor(s1, off, 64);
      s2 += __shfl_xor(s2, off, 64);
    }
    float mu = s1 * (1.0f / 64.0f);
    float var = s2 * (1.0f / 64.0f) - mu * mu;
    float inv = rsqrtf(var + 1e-5f);
    float y = (h - mu) * inv * gv + btv;
    out[(size_t)node * DIM + lane] = fmaxf(y, 0.0f);
  }
}

// ===========================================================================
// CSR-build path
// ===========================================================================

__global__ __launch_bounds__(256) void hist_kernel(const int* __restrict__ erow,
                                                   int* __restrict__ cnt,
                                                   int E) {
  int e = blockIdx.x * 256 + threadIdx.x;
  if (e < E) atomicAdd(&cnt[erow[e]], 1);
}

__global__ __launch_bounds__(256) void scan1_kernel(int* __restrict__ data,
                                                    int* __restrict__ partials,
                                                    int N) {
  __shared__ int wsum[4];
  int t = threadIdx.x;
  int base = blockIdx.x * 1024 + t * 4;
  int v0 = (base + 0 < N) ? data[base + 0] : 0;
  int v1 = (base + 1 < N) ? data[base + 1] : 0;
  int v2 = (base + 2 < N) ? data[base + 2] : 0;
  int v3 = (base + 3 < N) ? data[base + 3] : 0;
  int s = v0 + v1 + v2 + v3;
  int ps = s;
  int lane = t & 63;
#pragma unroll
  for (int off = 1; off < 64; off <<= 1) {
    int n = __shfl_up(ps, off, 64);
    if (lane >= off) ps += n;
  }
  if (lane == 63) wsum[t >> 6] = ps;
  __syncthreads();
  int woff = 0;
  for (int w = 0; w < (t >> 6); ++w) woff += wsum[w];
  int ex = woff + ps - s;
  if (base + 0 < N) data[base + 0] = ex;
  if (base + 1 < N) data[base + 1] = ex + v0;
  if (base + 2 < N) data[base + 2] = ex + v0 + v1;
  if (base + 3 < N) data[base + 3] = ex + v0 + v1 + v2;
  if (t == 255) partials[blockIdx.x] = woff + ps;
}

__global__ __launch_bounds__(256) void scan2_kernel(int* __restrict__ partials,
                                                    int nb) {
  __shared__ int wsum[4];
  int t = threadIdx.x;
  int v = (t < nb) ? partials[t] : 0;
  int ps = v;
  int lane = t & 63;
#pragma unroll
  for (int off = 1; off < 64; off <<= 1) {
    int n = __shfl_up(ps, off, 64);
    if (lane >= off) ps += n;
  }
  if (lane == 63) wsum[t >> 6] = ps;
  __syncthreads();
  int woff = 0;
  for (int w = 0; w < (t >> 6); ++w) woff += wsum[w];
  if (t < nb) partials[t] = woff + ps - v;
}

__global__ __launch_bounds__(256) void scan3_kernel(int* __restrict__ row_start,
                                                    int* __restrict__ fill,
                                                    const int* __restrict__ partials,
                                                    int N, int E) {
  int i = blockIdx.x * 256 + threadIdx.x;
  if (i < N) {
    int v = row_start[i] + partials[i >> 10];
    row_start[i] = v;
    fill[i] = v;
  }
  if (i == N) row_start[N] = E;
}

// 3) scatter edges into CSR slots — packed (col, val_bits) as one 8B store
__global__ __launch_bounds__(256) void scatter_sort_kernel(
    const int* __restrict__ erow, const int* __restrict__ ecol,
    const float* __restrict__ eval, int* __restrict__ fill,
    uint2* __restrict__ packed, int E) {
  int e = blockIdx.x * 256 + threadIdx.x;
  if (e >= E) return;
  int r = erow[e];
  uint2 p;
  p.x = (unsigned)ecol[e];
  p.y = __float_as_uint(eval[e]);
  int pos = atomicAdd(&fill[r], 1);
  packed[pos] = p;
}

// 4) fused gather (SpMM) + Linear + LayerNorm + ReLU.
__global__ __launch_bounds__(256) void fused_gather_linear_ln(
    const float* __restrict__ x, const uint2* __restrict__ packed,
    const int* __restrict__ row_start, const float* __restrict__ W,
    const float* __restrict__ bias, const float* __restrict__ gamma,
    const float* __restrict__ beta, float* __restrict__ out, int N) {
  __shared__ float Wt[64 * 65];
  __shared__ float xch[4][256];
  for (int i = threadIdx.x; i < 64 * 64; i += 256) {
    int d = i >> 6, k = i & 63;
    Wt[k * 65 + d] = W[i];
  }

  const int wave = threadIdx.x >> 6;
  const int lane = threadIdx.x & 63;
  const int grp = lane >> 4;
  const int lid = lane & 15;
  const int node0 = blockIdx.x * 16 + wave * 4;
  const int node = node0 + grp;

  float4 acc = make_float4(0.f, 0.f, 0.f, 0.f);
  if (node < N) {
    int s = row_start[node];
    int en = row_start[node + 1];
    int j = s;
    for (; j + 1 < en; j += 2) {
      uint2 p0 = packed[j];
      uint2 p1 = packed[j + 1];
      float v0 = __uint_as_float(p0.y);
      float v1 = __uint_as_float(p1.y);
      const float4 x0 =
          *reinterpret_cast<const float4*>(x + (size_t)p0.x * DIM + lid * 4);
      const float4 x1 =
          *reinterpret_cast<const float4*>(x + (size_t)p1.x * DIM + lid * 4);
      acc.x = fmaf(v0, x0.x, acc.x);
      acc.y = fmaf(v0, x0.y, acc.y);
      acc.z = fmaf(v0, x0.z, acc.z);
      acc.w = fmaf(v0, x0.w, acc.w);
      acc.x = fmaf(v1, x1.x, acc.x);
      acc.y = fmaf(v1, x1.y, acc.y);
      acc.z = fmaf(v1, x1.z, acc.z);
      acc.w = fmaf(v1, x1.w, acc.w);
    }
    if (j < en) {
      uint2 p0 = packed[j];
      float v0 = __uint_as_float(p0.y);
      const float4 x0 =
          *reinterpret_cast<const float4*>(x + (size_t)p0.x * DIM + lid * 4);
      acc.x = fmaf(v0, x0.x, acc.x);
      acc.y = fmaf(v0, x0.y, acc.y);
      acc.z = fmaf(v0, x0.z, acc.z);
      acc.w = fmaf(v0, x0.w, acc.w);
    }
  }
  __syncthreads();  // covers Wt staging too
  *reinterpret_cast<float4*>(&xch[wave][grp * 64 + lid * 4]) = acc;
  __syncthreads();

  float a0 = xch[wave][0 * 64 + lane];
  float a1 = xch[wave][1 * 64 + lane];
  float a2 = xch[wave][2 * 64 + lane];
  float a3 = xch[wave][3 * 64 + lane];

  float acc0 = 0.f, acc1 = 0.f, acc2 = 0.f, acc3 = 0.f;
#pragma unroll
  for (int k = 0; k < 64; ++k) {
    float w = Wt[k * 65 + lane];
    acc0 = fmaf(readlane_f(a0, k), w, acc0);
    acc1 = fmaf(readlane_f(a1, k), w, acc1);
    acc2 = fmaf(readlane_f(a2, k), w, acc2);
    acc3 = fmaf(readlane_f(a3, k), w, acc3);
  }

  const float bv = bias[lane];
  const float gv = gamma[lane];
  const float btv = beta[lane];

  float accs[4] = {acc0, acc1, acc2, acc3};
#pragma unroll
  for (int jj = 0; jj < 4; ++jj) {
    int nd = node0 + jj;
    if (nd >= N) continue;
    float h = accs[jj] + bv;
    float s1 = h, s2 = h * h;
#pragma unroll
    for (int off = 32; off; off >>= 1) {
      s1 += __shfl_xor(s1, off, 64);
      s2 += __shfl_xor(s2, off, 64);
    }
    float mu = s1 * (1.0f / 64.0f);
    float var = s2 * (1.0f / 64.0f) - mu * mu;
    float inv = rsqrtf(var + 1e-5f);
    float y = (h - mu) * inv * gv + btv;
    out[(size_t)nd * DIM + lane] = fmaxf(y, 0.0f);
  }
}

// ===========================================================================
extern "C" void kernel_launch(void* const* d_in, const int* in_sizes, int n_in,
                              void* d_out, int out_size, void* d_ws,
                              size_t ws_size, hipStream_t stream) {
  const float* x = (const float*)d_in[0];
  const int* erow = (const int*)d_in[1];
  const int* ecol = (const int*)d_in[2];
  const float* eval = (const float*)d_in[3];
  const float* W = (const float*)d_in[4];
  const float* bias = (const float*)d_in[5];
  const float* gamma = (const float*)d_in[6];
  const float* beta = (const float*)d_in[7];
  float* out = (float*)d_out;

  const int N = in_sizes[0] / DIM;
  const int E = in_sizes[1];

  const int nblk_scan = (N + 1023) / 1024;
  // row_start(N+1) + fill(N) + partials(256) ints, then 8B-aligned uint2[E]
  size_t int_words = (size_t)(N + 1) + N + 256;
  size_t packed_off = ((int_words * sizeof(int)) + 15) & ~(size_t)15;
  size_t need = packed_off + (size_t)E * sizeof(uint2);

  if (ws_size >= need && nblk_scan <= 256) {
    int* row_start = (int*)d_ws;            // N+1
    int* fill = row_start + (N + 1);        // N
    int* partials = fill + N;               // 256
    uint2* packed = (uint2*)((char*)d_ws + packed_off);  // E

    hipMemsetAsync(row_start, 0, (size_t)(N + 1) * sizeof(int), stream);

    int eblk = (E + 255) / 256;
    hist_kernel<<<eblk, 256, 0, stream>>>(erow, row_start, E);
    scan1_kernel<<<nblk_scan, 256, 0, stream>>>(row_start, partials, N);
    scan2_kernel<<<1, 256, 0, stream>>>(partials, nblk_scan);
    scan3_kernel<<<(N + 256) / 256, 256, 0, stream>>>(row_start, fill,
                                                      partials, N, E);
    scatter_sort_kernel<<<eblk, 256, 0, stream>>>(erow, ecol, eval, fill,
                                                  packed, E);
    fused_gather_linear_ln<<<(N + 15) / 16, 256, 0, stream>>>(
        x, packed, row_start, W, bias, gamma, beta, out, N);
  } else {
    const size_t agg_bytes = (size_t)N * DIM * sizeof(float);
    float* agg = (ws_size >= agg_bytes) ? (float*)d_ws : out;
    hipMemsetAsync(agg, 0, agg_bytes, stream);
    long long total = (long long)E * 16;
    int blocks = (int)((total + 255) / 256);
    scatter_kernel<<<blocks, 256, 0, stream>>>(x, erow, ecol, eval, agg, E);
    fused_linear_ln_relu<<<(N + 15) / 16, 256, 0, stream>>>(agg, W, bias,
                                                            gamma, beta, out, N);
  }
}